// Round 3
// baseline (590.555 us; speedup 1.0000x reference)
//
#include <hip/hip_runtime.h>

typedef __bf16 bf16;
typedef __bf16 bf16x2 __attribute__((ext_vector_type(2)));
typedef __bf16 bf16x8 __attribute__((ext_vector_type(8)));
typedef float f32x16 __attribute__((ext_vector_type(16)));

// workspace layout (bytes)
#define XT_BYTES  110166016L   // 64*82*82*128*2  bf16, zero-padded halo
#define W2_BYTES  18874368L    // 64*9*16*128*8*2 bf16, k-major [b][p][kc][och][8]
#define WS_NEEDED (XT_BYTES + W2_BYTES)

// async global->LDS, 16B per lane. LDS dest is wave-uniform base + lane*16.
__device__ __forceinline__ void async16(const void* g, void* l) {
    __builtin_amdgcn_global_load_lds((const __attribute__((address_space(1))) void*)g,
                                     (__attribute__((address_space(3))) void*)l, 16, 0, 0);
}

// ------------- transpose + halo zero: x[b][c][y][x] f32 -> xT[b][Y][X][c] bf16 (padded) -------------
__global__ void transpose_kernel(const float* __restrict__ x, bf16* __restrict__ xT) {
    __shared__ __align__(16) bf16 tile[64 * 68];
    int b = blockIdx.z, icb = blockIdx.y, pxb = blockIdx.x;
    int t = threadIdx.x;

    // halo zeroing: 5184 16B chunks per b, spread over the 200 blocks of this b
    {
        int bid2 = blockIdx.y * 100 + blockIdx.x;    // 0..199
        if (t < 26) {
            int k = bid2 * 26 + t;
            if (k < 5184) {
                long off;
                if (k < 1312) {
                    off = (long)k * 8;                                // row Y=0
                } else if (k < 2624) {
                    off = (long)81 * 82 * 128 + (long)(k - 1312) * 8; // row Y=81
                } else {
                    int r = k - 2624;
                    int Y = (r >> 5) + 1;        // 1..80
                    int side = (r >> 4) & 1;     // X=0 or X=81
                    int cq = r & 15;
                    off = ((long)Y * 82 + side * 81) * 128 + cq * 8;
                }
                *reinterpret_cast<uint4*>(xT + (long)b * 82 * 82 * 128 + off) =
                    make_uint4(0u, 0u, 0u, 0u);
            }
        }
    }

    int pl = t & 63;        // pixel lane
    int ig = t >> 6;        // 0..3
    const float* src = x + ((long)(b * 128 + icb * 64) * 6400) + pxb * 64;
    #pragma unroll
    for (int it = 0; it < 16; ++it) {
        int ic = ig * 16 + it;
        float v = src[(long)ic * 6400 + pl];
        tile[pl * 68 + ic] = (bf16)v;
    }
    __syncthreads();
    #pragma unroll
    for (int it = 0; it < 4; ++it) {
        int idx = it * 256 + t;
        int pxl = idx >> 4;          // 0..63
        int icq = idx & 15;          // 0..15 -> 4 ic each
        int px = pxb * 64 + pxl;
        int Y = px / 80 + 1, X = px % 80 + 1;
        uint2 v = *reinterpret_cast<const uint2*>(&tile[pxl * 68 + icq * 4]);
        *reinterpret_cast<uint2*>(&xT[(((long)b * 82 + Y) * 82 + X) * 128 + icb * 64 + icq * 4]) = v;
    }
}

// ------------- fused pool + attention: xT -> avg (LDS) -> sigmoid-scaled dyn weights -------------
// grid: 64 b x 4 channel-groups (32 och each), 256 threads.
// phase 1: avg[32ch][5][5] from 16x16 tiles.  phase 2: att conv + sigmoid -> W2k (k-major).
__global__ void pool_att(const bf16* __restrict__ xT, const float* __restrict__ weight,
                         const float* __restrict__ w_att, const float* __restrict__ b_att,
                         bf16* __restrict__ W2k) {
    __shared__ float part[16][16][2];
    __shared__ float avgs[32][25];
    int b = blockIdx.x >> 2, cg = blockIdx.x & 3;
    int t = threadIdx.x;
    int pg = t >> 4, ch2 = t & 15;     // pg = row-in-tile, ch2 = channel pair

    for (int ij = 0; ij < 25; ++ij) {
        int i = ij / 5, j = ij - i * 5;
        const bf16* src = xT + (((long)b * 82 + 1 + i * 16 + pg) * 82 + 1 + j * 16) * 128
                          + cg * 32 + ch2 * 2;
        float s0 = 0.f, s1 = 0.f;
        #pragma unroll
        for (int dx = 0; dx < 16; ++dx) {
            bf16x2 v = *reinterpret_cast<const bf16x2*>(src + dx * 128);
            s0 += (float)v[0];
            s1 += (float)v[1];
        }
        part[pg][ch2][0] = s0;
        part[pg][ch2][1] = s1;
        __syncthreads();
        if (t < 32) {
            int cr = t >> 1, half = t & 1;
            float s = 0.f;
            #pragma unroll
            for (int g = 0; g < 16; ++g) s += part[g][cr][half];
            avgs[cr * 2 + half][ij] = s * (1.0f / 256.0f);
        }
        __syncthreads();
    }

    // phase 2: each thread: ic = t&127, handles 16 och of this group
    int ic = t & 127, ochl = t >> 7;   // ochl in {0,1}
    #pragma unroll 2
    for (int ol = 0; ol < 16; ++ol) {
        int ochL = ochl * 16 + ol;     // 0..31
        int ochG = cg * 32 + ochL;
        long o = (long)ochG * 128 + ic;
        float wa[9];
        #pragma unroll
        for (int jj = 0; jj < 9; ++jj) wa[jj] = w_att[o * 9 + jj];
        float bias = b_att[o];
        const float* wst = weight + o * 9;
        const float* sa = &avgs[ochL][0];
        #pragma unroll
        for (int kh = 0; kh < 3; ++kh) {
            #pragma unroll
            for (int kw = 0; kw < 3; ++kw) {
                float z = bias;
                #pragma unroll
                for (int di = 0; di < 3; ++di)
                    #pragma unroll
                    for (int dj = 0; dj < 3; ++dj)
                        z += sa[(kh + di) * 5 + (kw + dj)] * wa[di * 3 + dj];
                float s = 1.0f / (1.0f + __expf(-z));
                float dw = wst[kh * 3 + kw] * s;
                int p = kh * 3 + kw;
                // k-major: W2k[b][p][kc=ic>>3][och 128][e=ic&7]
                W2k[((((long)b * 9 + p) * 16 + (ic >> 3)) * 128 + ochG) * 8 + (ic & 7)] = (bf16)dw;
            }
        }
    }
}

// ------------- main conv as implicit GEMM, bf16 MFMA 32x32x16, barrier-free K-loop -------------
// block: 128 och x 128 pix, 4 waves, wave = 64 och x 64 pix (2x2 of 32x32).
// X staged once in LDS (46KB -> 3 blocks/CU); A-fragments read per-wave straight from
// global W2k (k-major, fully coalesced 512B runs, L2/L3-resident) -> no K-loop barriers.
__global__ __launch_bounds__(256, 3)
void conv_gemm(const bf16* __restrict__ xT, const bf16* __restrict__ W2k,
               float* __restrict__ out) {
    __shared__ __align__(16) bf16 Xs[180 * 128];   // [pf=r*18+cx][ic], 16B chunks XOR-swizzled by (pf&7)
    int b = blockIdx.z;
    int px0 = blockIdx.x * 16;
    int py0 = blockIdx.y * 8;
    int t = threadIdx.x;
    int wave = t >> 6, lane = t & 63;
    int l31 = lane & 31, hl = lane >> 5;
    int ow = (wave >> 1) * 64;   // och offset of this wave
    int nw = (wave & 1) * 64;    // pixel offset of this wave

    // ---- prologue: stage X tile (10x18 rows, 128 ic) via global_load_lds; swizzle via
    // pre-swizzled global source (linear LDS dest).
    {
        const bf16* xsrc = xT + (((long)b * 82 + py0) * 82 + px0) * 128;
        for (int cidx = wave; cidx < 45; cidx += 4) {   // 2880 16B chunks = 45 wave-chunks
            int idx0 = cidx << 6;
            int idx = idx0 + lane;
            int pf = idx >> 4, icb = idx & 15;
            int r = pf / 18, cx = pf - r * 18;
            async16(xsrc + ((long)r * 82 + cx) * 128 + ((icb ^ (pf & 7)) << 3),
                    &Xs[idx0 * 8]);
        }
    }
    asm volatile("s_waitcnt vmcnt(0)" ::: "memory");
    __builtin_amdgcn_s_barrier();
    asm volatile("" ::: "memory");

    f32x16 acc[2][2];
    #pragma unroll
    for (int mi = 0; mi < 2; ++mi)
        #pragma unroll
        for (int ni = 0; ni < 2; ++ni)
            #pragma unroll
            for (int r = 0; r < 16; ++r) acc[mi][ni][r] = 0.f;

    int pfb = ((nw + l31) >> 4) * 18 + ((nw + l31) & 15);  // base pf for ni=0
    // A base: W2k elem offset = (((b*9+p)*16 + kc)*128 + och)*8 ; kc = ks*2+hl
    const bf16* Ab = W2k + (long)b * 9 * 16384 + hl * 1024 + (ow + l31) * 8;

    for (int p = 0; p < 9; ++p) {
        int kh = (p >= 6) ? 2 : ((p >= 3) ? 1 : 0);
        int kw = p - kh * 3;
        int pf0 = pfb + kh * 18 + kw;
        int pf1 = pf0 + 36;                     // ni=1: +2 rows of 18
        const bf16* Ap = Ab + (long)p * 16384;
        const bf16* B0 = &Xs[pf0 * 128];
        const bf16* B1 = &Xs[pf1 * 128];
        int s0 = pf0 & 7, s1 = pf1 & 7;
        __builtin_amdgcn_s_setprio(1);
        #pragma unroll
        for (int ks = 0; ks < 8; ++ks) {
            int kc = ks * 2 + hl;
            bf16x8 a0 = *reinterpret_cast<const bf16x8*>(Ap + ks * 2048);
            bf16x8 a1 = *reinterpret_cast<const bf16x8*>(Ap + ks * 2048 + 256);
            bf16x8 b0 = *reinterpret_cast<const bf16x8*>(B0 + ((kc ^ s0) << 3));
            bf16x8 b1 = *reinterpret_cast<const bf16x8*>(B1 + ((kc ^ s1) << 3));
            acc[0][0] = __builtin_amdgcn_mfma_f32_32x32x16_bf16(a0, b0, acc[0][0], 0, 0, 0);
            acc[0][1] = __builtin_amdgcn_mfma_f32_32x32x16_bf16(a0, b1, acc[0][1], 0, 0, 0);
            acc[1][0] = __builtin_amdgcn_mfma_f32_32x32x16_bf16(a1, b0, acc[1][0], 0, 0, 0);
            acc[1][1] = __builtin_amdgcn_mfma_f32_32x32x16_bf16(a1, b1, acc[1][1], 0, 0, 0);
        }
        __builtin_amdgcn_s_setprio(0);
    }

    // epilogue: 32x32 D layout: col=lane&31 (pixel), row=(reg&3)+8*(reg>>2)+4*(lane>>5) (och)
    #pragma unroll
    for (int mi = 0; mi < 2; ++mi) {
        #pragma unroll
        for (int ni = 0; ni < 2; ++ni) {
            int n = nw + ni * 32 + l31;
            int oy = py0 + (n >> 4), ox = px0 + (n & 15);
            float* ob = out + ((long)(b * 128 + ow + mi * 32 + 4 * hl) * 80 + oy) * 80 + ox;
            #pragma unroll
            for (int reg = 0; reg < 16; ++reg) {
                int row = (reg & 3) + 8 * (reg >> 2);
                ob[(long)row * 6400] = acc[mi][ni][reg];
            }
        }
    }
}

extern "C" void kernel_launch(void* const* d_in, const int* in_sizes, int n_in,
                              void* d_out, int out_size, void* d_ws, size_t ws_size,
                              hipStream_t stream) {
    const float* x      = (const float*)d_in[0];
    const float* weight = (const float*)d_in[1];
    const float* w_att  = (const float*)d_in[2];
    const float* b_att  = (const float*)d_in[3];
    float* out = (float*)d_out;

    if (ws_size < (size_t)WS_NEEDED) return;  // workspace too small: fail loudly (wrong output)

    char* ws = (char*)d_ws;
    bf16* xT  = (bf16*)ws;
    bf16* W2k = (bf16*)(ws + XT_BYTES);

    transpose_kernel<<<dim3(100, 2, 64), 256, 0, stream>>>(x, xT);
    pool_att<<<256, 256, 0, stream>>>(xT, weight, w_att, b_att, W2k);
    conv_gemm<<<dim3(5, 10, 64), 256, 0, stream>>>(xT, W2k, out);
}

// Round 4
// 503.446 us; speedup vs baseline: 1.1730x; 1.1730x over previous
//
#include <hip/hip_runtime.h>

typedef __bf16 bf16;
typedef __bf16 bf16x8 __attribute__((ext_vector_type(8)));
typedef float f32x16 __attribute__((ext_vector_type(16)));

// workspace layout (bytes)
#define XT_BYTES  110166016L   // 64*82*82*128*2  bf16, zero-padded halo
#define W2_BYTES  18874368L    // 64*9*16*128*8*2 bf16, k-major [b][p][kc][och][8]
#define AVG_BYTES 819200L      // 64*128*5*5 fp32
#define WS_NEEDED (XT_BYTES + W2_BYTES + AVG_BYTES)

// async global->LDS, 16B per lane. LDS dest is wave-uniform base + lane*16.
__device__ __forceinline__ void async16(const void* g, void* l) {
    __builtin_amdgcn_global_load_lds((const __attribute__((address_space(1))) void*)g,
                                     (__attribute__((address_space(3))) void*)l, 16, 0, 0);
}

// ------------- transpose + halo zero: x[b][c][y][x] f32 -> xT[b][Y][X][c] bf16 (padded) -------------
__global__ void transpose_kernel(const float* __restrict__ x, bf16* __restrict__ xT) {
    __shared__ __align__(16) bf16 tile[64 * 68];
    int b = blockIdx.z, icb = blockIdx.y, pxb = blockIdx.x;
    int t = threadIdx.x;

    // halo zeroing: 5184 16B chunks per b, spread over the 200 blocks of this b
    {
        int bid2 = blockIdx.y * 100 + blockIdx.x;    // 0..199
        if (t < 26) {
            int k = bid2 * 26 + t;
            if (k < 5184) {
                long off;
                if (k < 1312) {
                    off = (long)k * 8;                                // row Y=0
                } else if (k < 2624) {
                    off = (long)81 * 82 * 128 + (long)(k - 1312) * 8; // row Y=81
                } else {
                    int r = k - 2624;
                    int Y = (r >> 5) + 1;        // 1..80
                    int side = (r >> 4) & 1;     // X=0 or X=81
                    int cq = r & 15;
                    off = ((long)Y * 82 + side * 81) * 128 + cq * 8;
                }
                *reinterpret_cast<uint4*>(xT + (long)b * 82 * 82 * 128 + off) =
                    make_uint4(0u, 0u, 0u, 0u);
            }
        }
    }

    int pl = t & 63;        // pixel lane
    int ig = t >> 6;        // 0..3
    const float* src = x + ((long)(b * 128 + icb * 64) * 6400) + pxb * 64;
    #pragma unroll
    for (int it = 0; it < 16; ++it) {
        int ic = ig * 16 + it;
        float v = src[(long)ic * 6400 + pl];
        tile[pl * 68 + ic] = (bf16)v;
    }
    __syncthreads();
    #pragma unroll
    for (int it = 0; it < 4; ++it) {
        int idx = it * 256 + t;
        int pxl = idx >> 4;          // 0..63
        int icq = idx & 15;          // 0..15 -> 4 ic each
        int px = pxb * 64 + pxl;
        int Y = px / 80 + 1, X = px % 80 + 1;
        uint2 v = *reinterpret_cast<const uint2*>(&tile[pxl * 68 + icq * 4]);
        *reinterpret_cast<uint2*>(&xT[(((long)b * 82 + Y) * 82 + X) * 128 + icb * 64 + icq * 4]) = v;
    }
}

// ------------- pool from xT (bf16), wide grid: 1600 blocks -------------
__global__ void pool_kernel(const bf16* __restrict__ xT, float* __restrict__ avg) {
    __shared__ float part[256][8];
    int bid = blockIdx.x;
    int j = bid % 5; int t2 = bid / 5; int i = t2 % 5; int b = t2 / 5;
    int t = threadIdx.x;
    int pxg = t >> 4, cc = t & 15;
    const bf16* src = xT + (((long)b * 82 + 1 + i * 16 + pxg) * 82 + 1 + j * 16) * 128 + cc * 8;
    float s[8];
    #pragma unroll
    for (int e = 0; e < 8; ++e) s[e] = 0.f;
    #pragma unroll
    for (int dy = 0; dy < 16; ++dy) {
        bf16x8 v = *reinterpret_cast<const bf16x8*>(src + (long)dy * 128);
        #pragma unroll
        for (int e = 0; e < 8; ++e) s[e] += (float)v[e];
    }
    #pragma unroll
    for (int e = 0; e < 8; ++e) part[t][e] = s[e];
    __syncthreads();
    if (t < 128) {
        int cc2 = t >> 3, e = t & 7;
        float sum = 0.f;
        #pragma unroll
        for (int g = 0; g < 16; ++g) sum += part[g * 16 + cc2][e];
        avg[(((long)b * 128 + cc2 * 8 + e) * 5 + i) * 5 + j] = sum * (1.0f / 256.0f);
    }
}

// ------------- attention: avg -> att -> sigmoid -> dyn_w, W2k k-major [b][p][kc][och][8] -------------
__global__ void att_kernel(const float* __restrict__ avg, const float* __restrict__ weight,
                           const float* __restrict__ w_att, const float* __restrict__ b_att,
                           bf16* __restrict__ W2k) {
    __shared__ float sa[25];
    int b = blockIdx.x >> 7, och = blockIdx.x & 127;
    int ic = threadIdx.x;
    if (ic < 25) sa[ic] = avg[(long)blockIdx.x * 25 + ic];
    __syncthreads();
    int o = och * 128 + ic;
    float wa[9];
    #pragma unroll
    for (int j = 0; j < 9; ++j) wa[j] = w_att[(long)o * 9 + j];
    float bias = b_att[o];
    const float* wst = weight + (long)o * 9;
    #pragma unroll
    for (int kh = 0; kh < 3; ++kh) {
        #pragma unroll
        for (int kw = 0; kw < 3; ++kw) {
            float z = bias;
            #pragma unroll
            for (int di = 0; di < 3; ++di)
                #pragma unroll
                for (int dj = 0; dj < 3; ++dj)
                    z += sa[(kh + di) * 5 + (kw + dj)] * wa[di * 3 + dj];
            float s = 1.0f / (1.0f + __expf(-z));
            float dw = wst[kh * 3 + kw] * s;
            int p = kh * 3 + kw;
            // k-major: [b][p][kc=ic>>3][och][e=ic&7]
            W2k[((((long)b * 9 + p) * 16 + (ic >> 3)) * 128 + och) * 8 + (ic & 7)] = (bf16)dw;
        }
    }
}

// ------------- main conv: implicit GEMM, 32x32x16 MFMA, barrier-free, reg-pipelined A -------------
// block: 128 och x 128 pix, 4 waves, wave = 64 och x 64 pix (2x2 of 32x32).
// X staged once in LDS (46KB); A read from global W2k with a full-p double-buffered
// register pipeline (16 coalesced dwordx4 loads for p+1 in flight under p's 32 MFMAs).
__global__ __launch_bounds__(256, 2)
void conv_gemm(const bf16* __restrict__ xT, const bf16* __restrict__ W2k,
               float* __restrict__ out) {
    __shared__ __align__(16) bf16 Xs[180 * 128];   // [pf=r*18+cx][ic], 16B chunks XOR-swizzled by (pf&7)
    int b = blockIdx.z;
    int px0 = blockIdx.x * 16;
    int py0 = blockIdx.y * 8;
    int t = threadIdx.x;
    int wave = t >> 6, lane = t & 63;
    int l31 = lane & 31, hl = lane >> 5;
    int ow = (wave >> 1) * 64;   // och offset of this wave
    int nw = (wave & 1) * 64;    // pixel offset of this wave

    // A base: W2k elem offset = (((b*9+p)*16 + kc)*128 + och)*8 ; kc = ks*2+hl
    const bf16* Ab = W2k + (long)b * 9 * 16384 + hl * 1024 + (ow + l31) * 8;

    // ---- issue A(p=0) register loads first (latency overlaps X staging)
    bf16x8 Abuf[2][16];
    #pragma unroll
    for (int ks = 0; ks < 8; ++ks) {
        Abuf[0][ks * 2]     = *reinterpret_cast<const bf16x8*>(Ab + ks * 2048);
        Abuf[0][ks * 2 + 1] = *reinterpret_cast<const bf16x8*>(Ab + ks * 2048 + 256);
    }

    // ---- stage X tile (10x18 rows, 128 ic) via global_load_lds; swizzle via
    // pre-swizzled global source (linear LDS dest).
    {
        const bf16* xsrc = xT + (((long)b * 82 + py0) * 82 + px0) * 128;
        for (int cidx = wave; cidx < 45; cidx += 4) {   // 2880 16B chunks = 45 wave-chunks
            int idx0 = cidx << 6;
            int idx = idx0 + lane;
            int pf = idx >> 4, icb = idx & 15;
            int r = pf / 18, cx = pf - r * 18;
            async16(xsrc + ((long)r * 82 + cx) * 128 + ((icb ^ (pf & 7)) << 3),
                    &Xs[idx0 * 8]);
        }
    }
    asm volatile("s_waitcnt vmcnt(0)" ::: "memory");
    __builtin_amdgcn_s_barrier();
    asm volatile("" ::: "memory");

    f32x16 acc[2][2];
    #pragma unroll
    for (int mi = 0; mi < 2; ++mi)
        #pragma unroll
        for (int ni = 0; ni < 2; ++ni)
            #pragma unroll
            for (int r = 0; r < 16; ++r) acc[mi][ni][r] = 0.f;

    int pfb = ((nw + l31) >> 4) * 18 + ((nw + l31) & 15);  // base pf for ni=0

    #pragma unroll
    for (int p = 0; p < 9; ++p) {
        const int cur = p & 1, nxt = cur ^ 1;
        // issue next-p A loads (independent; in flight under this p's MFMAs)
        if (p < 8) {
            const bf16* Ap = Ab + (long)(p + 1) * 16384;
            #pragma unroll
            for (int ks = 0; ks < 8; ++ks) {
                Abuf[nxt][ks * 2]     = *reinterpret_cast<const bf16x8*>(Ap + ks * 2048);
                Abuf[nxt][ks * 2 + 1] = *reinterpret_cast<const bf16x8*>(Ap + ks * 2048 + 256);
            }
        }
        const int kh = p / 3, kw = p - kh * 3;
        int pf0 = pfb + kh * 18 + kw;
        int pf1 = pf0 + 36;                     // ni=1: +2 rows of 18
        const bf16* B0 = &Xs[pf0 * 128];
        const bf16* B1 = &Xs[pf1 * 128];
        int s0 = pf0 & 7, s1 = pf1 & 7;
        __builtin_amdgcn_s_setprio(1);
        #pragma unroll
        for (int ks = 0; ks < 8; ++ks) {
            int kc = ks * 2 + hl;
            bf16x8 b0 = *reinterpret_cast<const bf16x8*>(B0 + ((kc ^ s0) << 3));
            bf16x8 b1 = *reinterpret_cast<const bf16x8*>(B1 + ((kc ^ s1) << 3));
            acc[0][0] = __builtin_amdgcn_mfma_f32_32x32x16_bf16(Abuf[cur][ks * 2],     b0, acc[0][0], 0, 0, 0);
            acc[0][1] = __builtin_amdgcn_mfma_f32_32x32x16_bf16(Abuf[cur][ks * 2],     b1, acc[0][1], 0, 0, 0);
            acc[1][0] = __builtin_amdgcn_mfma_f32_32x32x16_bf16(Abuf[cur][ks * 2 + 1], b0, acc[1][0], 0, 0, 0);
            acc[1][1] = __builtin_amdgcn_mfma_f32_32x32x16_bf16(Abuf[cur][ks * 2 + 1], b1, acc[1][1], 0, 0, 0);
        }
        __builtin_amdgcn_s_setprio(0);
    }

    // epilogue: 32x32 D layout: col=lane&31 (pixel), row=(reg&3)+8*(reg>>2)+4*(lane>>5) (och)
    #pragma unroll
    for (int mi = 0; mi < 2; ++mi) {
        #pragma unroll
        for (int ni = 0; ni < 2; ++ni) {
            int n = nw + ni * 32 + l31;
            int oy = py0 + (n >> 4), ox = px0 + (n & 15);
            float* ob = out + ((long)(b * 128 + ow + mi * 32 + 4 * hl) * 80 + oy) * 80 + ox;
            #pragma unroll
            for (int reg = 0; reg < 16; ++reg) {
                int row = (reg & 3) + 8 * (reg >> 2);
                ob[(long)row * 6400] = acc[mi][ni][reg];
            }
        }
    }
}

extern "C" void kernel_launch(void* const* d_in, const int* in_sizes, int n_in,
                              void* d_out, int out_size, void* d_ws, size_t ws_size,
                              hipStream_t stream) {
    const float* x      = (const float*)d_in[0];
    const float* weight = (const float*)d_in[1];
    const float* w_att  = (const float*)d_in[2];
    const float* b_att  = (const float*)d_in[3];
    float* out = (float*)d_out;

    if (ws_size < (size_t)WS_NEEDED) return;  // workspace too small: fail loudly (wrong output)

    char* ws = (char*)d_ws;
    bf16* xT  = (bf16*)ws;
    bf16* W2k = (bf16*)(ws + XT_BYTES);
    float* avg = (float*)(ws + XT_BYTES + W2_BYTES);

    transpose_kernel<<<dim3(100, 2, 64), 256, 0, stream>>>(x, xT);
    pool_kernel<<<1600, 256, 0, stream>>>(xT, avg);
    att_kernel<<<8192, 128, 0, stream>>>(avg, weight, w_att, b_att, W2k);
    conv_gemm<<<dim3(5, 10, 64), 256, 0, stream>>>(xT, W2k, out);
}